// Round 7
// baseline (620.617 us; speedup 1.0000x reference)
//
#include <hip/hip_runtime.h>
#include <hip/hip_cooperative_groups.h>

namespace cg = cooperative_groups;

#define H 128
#define RREL 8
#define NJ 9        // 8 relations + root
#define MT 32       // dsts per layer-tile
#define LROW 1160   // agg LDS row stride in elems (1152 + 8 pad)

typedef short bf16x8 __attribute__((ext_vector_type(8)));
typedef float f32x4 __attribute__((ext_vector_type(4)));
typedef unsigned short u16x8 __attribute__((ext_vector_type(8)));

static __device__ __forceinline__ unsigned short f2bf(float f) {
    unsigned int u = __float_as_uint(f);
    unsigned int r = (u + 0x7fffu + ((u >> 16) & 1u)) >> 16;
    return (unsigned short)r;
}
static __device__ __forceinline__ float bf2f(unsigned short u) {
    return __uint_as_float(((unsigned int)u) << 16);
}

struct Args {
    const int* ei; const int* et; const float* x;
    const float* W1; const float* r1; const float* b1;
    const float* W2; const float* r2; const float* b2;
    float* out;
    int* cnt; int* rploc; int* bsum; int* ctr;   // ctr[0]=layer1 queue, ctr[1]=layer2 queue
    int* rowptr; int* rowptr2; float* inv; int* packed;
    unsigned short* WTa1; unsigned short* WTa2; float* biasP;
    unsigned short* xb; unsigned short* hb;
    int N; int E; int ntiles; int nchunk;
};

// accumulate one edge (branchless, rel-sorted, flush-every-edge: last write per
// (d,r) slot is the full sum; clamped tail dups add 0 and rewrite same value)
#define ACC(EE, XV, VV)                                                        \
    do {                                                                       \
        int r_ = ((VV) >> 20) & 7;                                             \
        bool nr_ = (r_ != rcur);                                               \
        float ivc_ = __shfl(ivl, gbase + r_);                                  \
        bool pr_ = (hb + (EE)) < m;                                            \
        u16x8 o_;                                                              \
        _Pragma("unroll")                                                      \
        for (int j = 0; j < 8; ++j) {                                          \
            float xx_ = bf2f((unsigned short)(XV)[j]);                         \
            float t0_ = nr_ ? 0.f : tmp[j];                                    \
            tmp[j] = t0_ + (pr_ ? xx_ : 0.f);                                  \
            o_[j] = f2bf(ivc_ * tmp[j]);                                       \
        }                                                                      \
        *(u16x8*)&rowp[r_ * H + kc] = o_;                                      \
        rcur = r_;                                                             \
    } while (0)

// One fused RGCN layer tile (32 dsts): aggregate in LDS then MFMA transform.
// (identical to the proven 97 us structure; Mbase from dynamic tile id)
static __device__ void layer_tile(unsigned short* aggS, const unsigned short* xin,
                                  const unsigned short* WTa, const float* biasP,
                                  const float* inv, const int* rowptr, const int* packed,
                                  float* outf, unsigned short* outb,
                                  int N, int relu, int tile) {
    const int t = threadIdx.x;
    const int l = t & 63;
    const int w = t >> 6;
    const int g16 = t >> 4;
    const int fl = t & 15;
    const int kc = fl * 8;
    const int gbase = l & 48;
    const int Mbase = tile * MT;
    const int d = Mbase + g16;
    const bool valid = d < N;

    unsigned short* rowp = &aggS[g16 * LROW];
    {
        u16x8 z = {0, 0, 0, 0, 0, 0, 0, 0};
#pragma unroll
        for (int c = 0; c < 8; ++c) *(u16x8*)&rowp[(c * 16 + fl) * 8] = z;
        if (valid) {
            *(u16x8*)&rowp[RREL * H + kc] = *(const u16x8*)&xin[(size_t)d * H + kc];
        } else {
            *(u16x8*)&rowp[RREL * H + kc] = z;
        }
    }

    int rp = 0;
    if (valid && fl < 2) rp = rowptr[d + fl];
    float ivl = 0.f;
    if (valid && fl < 8) ivl = inv[(size_t)d * RREL + fl];
    int beg = __shfl(rp, gbase);
    int end = __shfl(rp, gbase + 1);

    if (end > beg) {
        float tmp[8] = {};
        int rcur = 100;
        int idx0 = beg + fl; if (idx0 > end - 1) idx0 = end - 1;
        int pk = packed[idx0];
        for (int i = beg; i < end; i += 16) {
            int ni = i + 16 + fl; if (ni > end - 1) ni = end - 1;
            int pkN = packed[ni];
            int m = end - i;
            if (m > 16) m = 16;
#pragma unroll
            for (int half = 0; half < 2; ++half) {
                const int hb = half * 8;
                int v0 = __shfl(pk, gbase + hb + 0);
                int v1 = __shfl(pk, gbase + hb + 1);
                int v2 = __shfl(pk, gbase + hb + 2);
                int v3 = __shfl(pk, gbase + hb + 3);
                int v4 = __shfl(pk, gbase + hb + 4);
                int v5 = __shfl(pk, gbase + hb + 5);
                int v6 = __shfl(pk, gbase + hb + 6);
                int v7 = __shfl(pk, gbase + hb + 7);
                u16x8 x0 = *(const u16x8*)&xin[(size_t)(v0 & 0xFFFFF) * H + kc];
                u16x8 x1 = *(const u16x8*)&xin[(size_t)(v1 & 0xFFFFF) * H + kc];
                u16x8 x2 = *(const u16x8*)&xin[(size_t)(v2 & 0xFFFFF) * H + kc];
                u16x8 x3 = *(const u16x8*)&xin[(size_t)(v3 & 0xFFFFF) * H + kc];
                u16x8 x4 = *(const u16x8*)&xin[(size_t)(v4 & 0xFFFFF) * H + kc];
                u16x8 x5 = *(const u16x8*)&xin[(size_t)(v5 & 0xFFFFF) * H + kc];
                u16x8 x6 = *(const u16x8*)&xin[(size_t)(v6 & 0xFFFFF) * H + kc];
                u16x8 x7 = *(const u16x8*)&xin[(size_t)(v7 & 0xFFFFF) * H + kc];
                __builtin_amdgcn_sched_barrier(0);
                ACC(0, x0, v0);
                ACC(1, x1, v1);
                ACC(2, x2, v2);
                ACC(3, x3, v3);
                ACC(4, x4, v4);
                ACC(5, x5, v5);
                ACC(6, x6, v6);
                ACC(7, x7, v7);
            }
            pk = pkN;
        }
    }

    __syncthreads();

    // Phase 2: wave w owns output cols [w*16, w*16+16)
    const int colb = l & 15, quad = l >> 4;
    const int fcol = w * 16 + colb;
    const f32x4 fz = {0.f, 0.f, 0.f, 0.f};
    f32x4 acc0 = fz, acc1 = fz;
    const unsigned short* arow0 = &aggS[colb * LROW];
    const unsigned short* arow1 = &aggS[(16 + colb) * LROW];
#pragma unroll
    for (int j = 0; j < NJ; ++j) {
#pragma unroll
        for (int ks = 0; ks < 4; ++ks) {
            const int kl = ks * 32 + quad * 8;
            bf16x8 b = *(const bf16x8*)&WTa[((size_t)j * H + fcol) * H + kl];
            bf16x8 a0 = *(const bf16x8*)&arow0[j * H + kl];
            bf16x8 a1 = *(const bf16x8*)&arow1[j * H + kl];
            acc0 = __builtin_amdgcn_mfma_f32_16x16x32_bf16(a0, b, acc0, 0, 0, 0);
            acc1 = __builtin_amdgcn_mfma_f32_16x16x32_bf16(a1, b, acc1, 0, 0, 0);
        }
    }

    __syncthreads();  // aggS reads done; reuse as fp32 staging [32][132]
    float* stg = (float*)aggS;
    const float bcol = biasP[fcol];
#pragma unroll
    for (int i = 0; i < 4; ++i) {
        float v0 = acc0[i] + bcol;
        float v1 = acc1[i] + bcol;
        if (relu) { v0 = fmaxf(v0, 0.f); v1 = fmaxf(v1, 0.f); }
        stg[(quad * 4 + i) * 132 + fcol] = v0;
        stg[(16 + quad * 4 + i) * 132 + fcol] = v1;
    }
    __syncthreads();
    {
        int row = t >> 4;
        int dd = Mbase + row;
        if (dd < N) {
            int c0 = fl * 8;
            f32x4 p0 = *(const f32x4*)&stg[row * 132 + c0];
            f32x4 p1 = *(const f32x4*)&stg[row * 132 + c0 + 4];
            if (outf) {
                *(f32x4*)&outf[(size_t)dd * H + c0] = p0;
                *(f32x4*)&outf[(size_t)dd * H + c0 + 4] = p1;
            } else {
                u16x8 o;
#pragma unroll
                for (int j = 0; j < 4; ++j) { o[j] = f2bf(p0[j]); o[4 + j] = f2bf(p1[j]); }
                *(u16x8*)&outb[(size_t)dd * H + c0] = o;
            }
        }
    }
}

// Single persistent cooperative kernel: preproc phases + both layers,
// separated by grid.sync(). Layer tiles via dynamic atomic work queue.
__global__ __launch_bounds__(512) void mega_kernel(Args a) {
    __shared__ __align__(16) unsigned short smem[MT * LROW];   // 74240 B
    __shared__ int tileS;
    cg::grid_group grid = cg::this_grid();
    const int t = threadIdx.x;
    const int bid = blockIdx.x;
    const int nb = gridDim.x;
    const long gid = (long)bid * 512 + t;
    const long gsz = (long)nb * 512;

    // ---- P0: zero cnt, reset queues; weight transpose + bias; x -> bf16 ----
    if (gid == 0) { a.ctr[0] = 0; a.ctr[1] = 0; }
    for (long i = gid; i < (long)a.N * RREL; i += gsz) a.cnt[i] = 0;
    {
        const long per = (long)NJ * H * H;
        const long total = per + 2 * H + (long)a.N * H;
        for (long id = gid; id < total; id += gsz) {
            if (id < per) {
                int j = (int)(id / (H * H));
                int fk = (int)(id - (long)j * (H * H));
                int f = fk >> 7, k = fk & 127;
                float v1 = (j < RREL) ? a.W1[((size_t)j * H + k) * H + f] : a.r1[(size_t)k * H + f];
                a.WTa1[id] = f2bf(v1);
                float v2 = (j < RREL) ? a.W2[((size_t)j * H + k) * H + f] : a.r2[(size_t)k * H + f];
                a.WTa2[id] = f2bf(v2);
            } else if (id < per + 2 * H) {
                int c = (int)(id - per);
                a.biasP[c] = (c < H) ? a.b1[c] : a.b2[c - H];
            } else {
                long i2 = id - per - 2 * H;
                a.xb[i2] = f2bf(a.x[i2]);
            }
        }
    }
    grid.sync();

    // ---- P1: per-(dst,rel) counts ----
    for (long e = gid; e < a.E; e += gsz) {
        int d = a.ei[a.E + e], r = a.et[e];
        atomicAdd(&a.cnt[(size_t)d * RREL + r], 1);
    }
    grid.sync();

    // ---- P2: per-512-chunk scan of dst degrees ----
    int* sS = (int*)smem;
    for (int c = bid; c < a.nchunk; c += nb) {
        int d = c * 512 + t;
        int v = 0;
        if (d < a.N) {
#pragma unroll
            for (int r = 0; r < RREL; ++r) v += a.cnt[(size_t)d * RREL + r];
        }
        sS[t] = v;
        __syncthreads();
#pragma unroll
        for (int off = 1; off < 512; off <<= 1) {
            int u = 0;
            if (t >= off) u = sS[t - off];
            __syncthreads();
            sS[t] += u;
            __syncthreads();
        }
        if (d < a.N) a.rploc[d] = sS[t] - v;
        if (t == 511) a.bsum[c] = sS[511];
        __syncthreads();
    }
    grid.sync();

    // ---- P3: finalize rowptr / rowptr2 / inv (inline scan of bsum) ----
    {
        int v = (t < a.nchunk) ? a.bsum[t] : 0;
        sS[t] = v;
        __syncthreads();
#pragma unroll
        for (int off = 1; off < 512; off <<= 1) {
            int u = 0;
            if (t >= off) u = sS[t - off];
            __syncthreads();
            sS[t] += u;
            __syncthreads();
        }
        for (int c = bid; c < a.nchunk; c += nb) {
            int boffB = (c == 0) ? 0 : sS[c - 1];
            int d = c * 512 + t;
            if (d < a.N) {
                int rp = a.rploc[d] + boffB;
                a.rowptr[d] = rp;
                int run = rp;
#pragma unroll
                for (int r = 0; r < RREL; ++r) {
                    int cc = a.cnt[(size_t)d * RREL + r];
                    a.rowptr2[(size_t)d * RREL + r] = run;
                    a.inv[(size_t)d * RREL + r] = 1.0f / (float)max(cc, 1);
                    run += cc;
                }
                if (d == a.N - 1) a.rowptr[a.N] = run;
            }
        }
    }
    grid.sync();

    // ---- P4: fill (cnt reused as countdown cursor; in-bin order irrelevant) ----
    for (long e = gid; e < a.E; e += gsz) {
        int d = a.ei[a.E + e], r = a.et[e];
        size_t bin = (size_t)d * RREL + r;
        int old = atomicSub(&a.cnt[bin], 1);
        a.packed[a.rowptr2[bin] + old - 1] = a.ei[e] | (r << 20);
    }
    grid.sync();

    // ---- P5: layer 1 (dynamic tile queue) ----
    for (;;) {
        if (t == 0) tileS = atomicAdd(&a.ctr[0], 1);
        __syncthreads();
        int tile = tileS;
        if (tile >= a.ntiles) break;
        layer_tile(smem, a.xb, a.WTa1, a.biasP, a.inv, a.rowptr, a.packed,
                   nullptr, a.hb, a.N, 1, tile);
        __syncthreads();
    }
    grid.sync();

    // ---- P6: layer 2 ----
    for (;;) {
        if (t == 0) tileS = atomicAdd(&a.ctr[1], 1);
        __syncthreads();
        int tile = tileS;
        if (tile >= a.ntiles) break;
        layer_tile(smem, a.hb, a.WTa2, a.biasP + H, a.inv, a.rowptr, a.packed,
                   a.out, nullptr, a.N, 0, tile);
        __syncthreads();
    }
}

extern "C" void kernel_launch(void* const* d_in, const int* in_sizes, int n_in,
                              void* d_out, int out_size, void* d_ws, size_t ws_size,
                              hipStream_t stream) {
    const int E = in_sizes[1];
    const int N = in_sizes[2] / H;

    char* base = (char*)d_ws;
    size_t off = 0;
    auto take = [&](size_t bytes) { size_t o = off; off = (off + bytes + 63) & ~(size_t)63; return o; };

    Args a;
    a.ei = (const int*)d_in[0];
    a.et = (const int*)d_in[1];
    a.x  = (const float*)d_in[2];
    a.W1 = (const float*)d_in[3];
    a.r1 = (const float*)d_in[4];
    a.b1 = (const float*)d_in[5];
    a.W2 = (const float*)d_in[6];
    a.r2 = (const float*)d_in[7];
    a.b2 = (const float*)d_in[8];
    a.out = (float*)d_out;

    a.cnt     = (int*)  (base + take((size_t)N * RREL * 4));
    a.rploc   = (int*)  (base + take((size_t)N * 4));
    a.bsum    = (int*)  (base + take(512 * 4));
    a.ctr     = (int*)  (base + take(2 * 4));
    a.rowptr  = (int*)  (base + take(((size_t)N + 1) * 4));
    a.rowptr2 = (int*)  (base + take((size_t)N * RREL * 4));
    a.inv     = (float*)(base + take((size_t)N * RREL * 4));
    a.packed  = (int*)  (base + take((size_t)E * 4));
    a.WTa1    = (unsigned short*)(base + take((size_t)NJ * H * H * 2));
    a.WTa2    = (unsigned short*)(base + take((size_t)NJ * H * H * 2));
    a.biasP   = (float*)(base + take(2 * H * 4));
    a.xb      = (unsigned short*)(base + take((size_t)N * H * 2));
    a.hb      = (unsigned short*)(base + take((size_t)N * H * 2));
    (void)ws_size;

    a.N = N;
    a.E = E;
    a.ntiles = (N + MT - 1) / MT;
    a.nchunk = (N + 511) / 512;

    static int g_grid = 0;
    if (g_grid == 0) {
        int occ = 0;
        (void)hipOccupancyMaxActiveBlocksPerMultiprocessor(&occ, mega_kernel, 512, 0);
        int dev = 0, ncu = 256;
        if (hipGetDevice(&dev) == hipSuccess) {
            hipDeviceProp_t prop;
            if (hipGetDeviceProperties(&prop, dev) == hipSuccess) ncu = prop.multiProcessorCount;
        }
        if (occ < 1) occ = 1;
        long cap = (long)occ * ncu;
        g_grid = (int)(cap < 512 ? cap : 512);
        if (g_grid < 1) g_grid = 1;
    }

    void* params[] = {(void*)&a};
    hipLaunchCooperativeKernel((void*)mega_kernel, dim3(g_grid), dim3(512), params, 0, stream);
}